// Round 2
// baseline (513.351 us; speedup 1.0000x reference)
//
#include <hip/hip_runtime.h>
#include <hip/hip_bf16.h>
#include <math.h>

#define B_  4
#define S_  2048
#define D_  512
#define H_  8
#define DK_ 64
#define M_  (B_ * S_)   // 8192

using bf16   = __bf16;
using bf16x8 = __bf16 __attribute__((ext_vector_type(8)));
using f32x4  = float __attribute__((ext_vector_type(4)));

#define MFMA16(a, b, c) __builtin_amdgcn_mfma_f32_16x16x32_bf16((a), (b), (c), 0, 0, 0)

__device__ __forceinline__ bf16x8 ldg8(const bf16* p) {
    return *reinterpret_cast<const bf16x8*>(p);
}

// load 8 consecutive f32, convert to bf16x8 (two dwordx4 loads + cvt)
__device__ __forceinline__ bf16x8 ldf8(const float* p) {
    f32x4 a = *reinterpret_cast<const f32x4*>(p);
    f32x4 b = *reinterpret_cast<const f32x4*>(p + 4);
    bf16x8 r;
    #pragma unroll
    for (int i = 0; i < 4; ++i) { r[i] = (bf16)a[i]; r[i + 4] = (bf16)b[i]; }
    return r;
}

// ---------------------------------------------------------------------------
// QKV projection: Y = X @ W^T, X:[M_,D_] f32, W:[D_,D_] f32 (both K-contig).
// Output written permuted into [3][B*H][S][DK] bf16 for the attention stage.
// ---------------------------------------------------------------------------
__global__ __launch_bounds__(256) void proj_qkv(
    const float* __restrict__ Xq, const float* __restrict__ Xk, const float* __restrict__ Xv,
    const float* __restrict__ Wq, const float* __restrict__ Wk, const float* __restrict__ Wv,
    bf16* __restrict__ OutBase)
{
    const int z = blockIdx.z;
    const float* X = (z == 0) ? Xq : (z == 1) ? Xk : Xv;
    const float* W = (z == 0) ? Wq : (z == 1) ? Wk : Wv;
    bf16* Y = OutBase + (size_t)z * M_ * D_;

    const int lane = threadIdx.x & 63;
    const int wave = threadIdx.x >> 6;
    const int lc = lane & 15;        // A: m-within-16 | B: n-within-16 | C: col
    const int lg = lane >> 4;        // quad 0..3
    const int n0 = blockIdx.x * 64;
    const int m0 = blockIdx.y * 64 + wave * 16;

    f32x4 acc[4] = {};

    const float* arow = X + (size_t)(m0 + lc) * D_ + lg * 8;
    const float* brow = W + (size_t)(n0 + lc) * D_ + lg * 8;

    #pragma unroll
    for (int k0 = 0; k0 < D_; k0 += 32) {
        bf16x8 a = ldf8(arow + k0);
        #pragma unroll
        for (int j = 0; j < 4; ++j) {
            bf16x8 b = ldf8(brow + (size_t)j * 16 * D_ + k0);
            acc[j] = MFMA16(a, b, acc[j]);
        }
    }

    #pragma unroll
    for (int j = 0; j < 4; ++j) {
        #pragma unroll
        for (int r = 0; r < 4; ++r) {
            const int row = m0 + lg * 4 + r;           // m index = b*S + s
            const int col = n0 + j * 16 + lc;          // n index = h*64 + d
            const size_t oidx =
                ((((size_t)(row >> 11) * H_ + (col >> 6)) * S_ + (row & (S_ - 1))) << 6)
                + (col & 63);
            Y[oidx] = (bf16)acc[j][r];
        }
    }
}

// ---------------------------------------------------------------------------
// Output projection: Y = ctx @ Wo^T; ctx bf16 [M_,D_] (ws), Wo f32, Y f32 out.
// ---------------------------------------------------------------------------
__global__ __launch_bounds__(256) void proj_out(
    const bf16* __restrict__ X, const float* __restrict__ W, float* __restrict__ Y)
{
    const int lane = threadIdx.x & 63;
    const int wave = threadIdx.x >> 6;
    const int lc = lane & 15;
    const int lg = lane >> 4;
    const int n0 = blockIdx.x * 64;
    const int m0 = blockIdx.y * 64 + wave * 16;

    f32x4 acc[4] = {};

    const bf16* arow = X + (size_t)(m0 + lc) * D_ + lg * 8;
    const float* brow = W + (size_t)(n0 + lc) * D_ + lg * 8;

    #pragma unroll
    for (int k0 = 0; k0 < D_; k0 += 32) {
        bf16x8 a = ldg8(arow + k0);
        #pragma unroll
        for (int j = 0; j < 4; ++j) {
            bf16x8 b = ldf8(brow + (size_t)j * 16 * D_ + k0);
            acc[j] = MFMA16(a, b, acc[j]);
        }
    }

    #pragma unroll
    for (int j = 0; j < 4; ++j) {
        #pragma unroll
        for (int r = 0; r < 4; ++r) {
            const int row = m0 + lg * 4 + r;
            const int col = n0 + j * 16 + lc;
            Y[(size_t)row * D_ + col] = acc[j][r];
        }
    }
}

// ---------------------------------------------------------------------------
// Causal flash attention over [B*H] planes of [S, DK] bf16.
// Block = 256 threads (4 waves); block handles 64 q-rows; wave handles 16.
// ---------------------------------------------------------------------------
__global__ __launch_bounds__(256) void attn(
    const bf16* __restrict__ QKV, bf16* __restrict__ Ctx)
{
    const int bh = blockIdx.y;
    const int b = bh >> 3, h = bh & 7;
    const int q0 = blockIdx.x * 64;
    const size_t plane = (size_t)S_ * DK_;
    const bf16* Q  = QKV + (size_t)bh * plane;
    const bf16* Kp = QKV + (size_t)(B_ * H_) * plane + (size_t)bh * plane;
    const bf16* Vp = QKV + 2 * (size_t)(B_ * H_) * plane + (size_t)bh * plane;

    const int lane = threadIdx.x & 63;
    const int wave = threadIdx.x >> 6;
    const int lc = lane & 15;
    const int lg = lane >> 4;
    const int qw = q0 + wave * 16;

    __shared__ bf16 Vt[64][72];       // V^T: Vt[d][k_local], +8 pad breaks conflicts
    __shared__ bf16 Pl[4][16][72];    // per-wave P round-trip: [q_local][k_local]

    bf16x8 qf0 = ldg8(Q + (size_t)(qw + lc) * DK_ + lg * 8);
    bf16x8 qf1 = ldg8(Q + (size_t)(qw + lc) * DK_ + 32 + lg * 8);

    f32x4 accO[4] = {};               // C layout: row q=lg*4+r, col d=t*16+lc
    float mi[4], li[4];
    #pragma unroll
    for (int r = 0; r < 4; ++r) { mi[r] = -1e30f; li[r] = 0.f; }

    const float scale = 0.125f;       // 1/sqrt(64)
    const float NEG = -1e30f;

    for (int k0 = 0; k0 < q0 + 64; k0 += 64) {
        __syncthreads();              // protect Vt from previous iteration's readers
        {
            const int kr = threadIdx.x >> 2;
            const int c0 = (threadIdx.x & 3) * 16;
            bf16x8 va = ldg8(Vp + (size_t)(k0 + kr) * DK_ + c0);
            bf16x8 vb = ldg8(Vp + (size_t)(k0 + kr) * DK_ + c0 + 8);
            #pragma unroll
            for (int c = 0; c < 8; ++c) Vt[c0 + c][kr] = va[c];
            #pragma unroll
            for (int c = 0; c < 8; ++c) Vt[c0 + 8 + c][kr] = vb[c];
        }
        __syncthreads();

        // ---- scores S = Q K^T for 16 q x 64 k ------------------------------
        f32x4 sc[4] = {};
        #pragma unroll
        for (int t = 0; t < 4; ++t) {
            bf16x8 b0 = ldg8(Kp + (size_t)(k0 + t * 16 + lc) * DK_ + lg * 8);
            bf16x8 b1 = ldg8(Kp + (size_t)(k0 + t * 16 + lc) * DK_ + 32 + lg * 8);
            sc[t] = MFMA16(qf0, b0, sc[t]);
            sc[t] = MFMA16(qf1, b1, sc[t]);
        }

        // ---- online softmax ------------------------------------------------
        float mnew[4], alpha[4];
        #pragma unroll
        for (int r = 0; r < 4; ++r) {
            const int q = qw + lg * 4 + r;
            float mx = mi[r];
            #pragma unroll
            for (int t = 0; t < 4; ++t) {
                const int kpos = k0 + t * 16 + lc;
                float s = (kpos <= q) ? sc[t][r] * scale : NEG;
                sc[t][r] = s;
                mx = fmaxf(mx, s);
            }
            #pragma unroll
            for (int off = 8; off > 0; off >>= 1)
                mx = fmaxf(mx, __shfl_xor(mx, off, 16));
            mnew[r] = mx;
            alpha[r] = __expf(mi[r] - mx);   // first tile: exp(-1e30 - mx) = 0
            mi[r] = mx;
        }
        #pragma unroll
        for (int r = 0; r < 4; ++r) {
            float rs = 0.f;
            #pragma unroll
            for (int t = 0; t < 4; ++t) {
                float p = __expf(sc[t][r] - mnew[r]);   // masked -> underflow to 0
                sc[t][r] = p;
                rs += p;
            }
            #pragma unroll
            for (int off = 8; off > 0; off >>= 1)
                rs += __shfl_xor(rs, off, 16);
            li[r] = li[r] * alpha[r] + rs;
            #pragma unroll
            for (int t = 0; t < 4; ++t) accO[t][r] *= alpha[r];
        }

        // ---- P: C-layout -> A-layout via per-wave LDS ----------------------
        #pragma unroll
        for (int t = 0; t < 4; ++t) {
            #pragma unroll
            for (int r = 0; r < 4; ++r)
                Pl[wave][lg * 4 + r][t * 16 + lc] = (bf16)sc[t][r];
        }
        bf16x8 p0 = *reinterpret_cast<const bf16x8*>(&Pl[wave][lc][lg * 8]);
        bf16x8 p1 = *reinterpret_cast<const bf16x8*>(&Pl[wave][lc][32 + lg * 8]);

        // ---- O += P V ------------------------------------------------------
        #pragma unroll
        for (int t = 0; t < 4; ++t) {
            bf16x8 v0 = *reinterpret_cast<const bf16x8*>(&Vt[t * 16 + lc][lg * 8]);
            bf16x8 v1 = *reinterpret_cast<const bf16x8*>(&Vt[t * 16 + lc][32 + lg * 8]);
            accO[t] = MFMA16(p0, v0, accO[t]);
            accO[t] = MFMA16(p1, v1, accO[t]);
        }
    }

    // ---- epilogue: ctx[b, q, h*64 + d] = O / l -----------------------------
    #pragma unroll
    for (int t = 0; t < 4; ++t) {
        #pragma unroll
        for (int r = 0; r < 4; ++r) {
            const int q = qw + lg * 4 + r;
            const float o = accO[t][r] / li[r];
            Ctx[((size_t)b * S_ + q) * D_ + h * 64 + t * 16 + lc] = (bf16)o;
        }
    }
}

extern "C" void kernel_launch(void* const* d_in, const int* in_sizes, int n_in,
                              void* d_out, int out_size, void* d_ws, size_t ws_size,
                              hipStream_t stream)
{
    const float* Xq = (const float*)d_in[0];
    const float* Xk = (const float*)d_in[1];
    const float* Xv = (const float*)d_in[2];
    const float* Wq = (const float*)d_in[3];
    const float* Wk = (const float*)d_in[4];
    const float* Wv = (const float*)d_in[5];
    const float* Wo = (const float*)d_in[6];
    float* out = (float*)d_out;

    bf16* qkv = (bf16*)d_ws;                          // [3][B*H][S][DK] bf16
    bf16* ctx = qkv + (size_t)3 * M_ * D_;            // [B][S][D] bf16

    proj_qkv<<<dim3(D_ / 64, M_ / 64, 3), 256, 0, stream>>>(Xq, Xk, Xv, Wq, Wk, Wv, qkv);
    attn<<<dim3(S_ / 64, B_ * H_), 256, 0, stream>>>(qkv, ctx);
    proj_out<<<dim3(D_ / 64, M_ / 64), 256, 0, stream>>>(ctx, Wo, out);
}

// Round 3
// 303.235 us; speedup vs baseline: 1.6929x; 1.6929x over previous
//
#include <hip/hip_runtime.h>
#include <hip/hip_bf16.h>
#include <math.h>

#define B_  4
#define S_  2048
#define D_  512
#define H_  8
#define DK_ 64
#define M_  (B_ * S_)   // 8192

using bf16   = __bf16;
using bf16x8 = __bf16 __attribute__((ext_vector_type(8)));
using f32x4  = float __attribute__((ext_vector_type(4)));

#define MFMA16(a, b, c) __builtin_amdgcn_mfma_f32_16x16x32_bf16((a), (b), (c), 0, 0, 0)

typedef __attribute__((address_space(3))) void       lds_void;
typedef const __attribute__((address_space(1))) void gbl_void;

__device__ __forceinline__ void async16(const bf16* g, bf16* lds) {
    __builtin_amdgcn_global_load_lds((gbl_void*)g, (lds_void*)lds, 16, 0, 0);
}

__device__ __forceinline__ bf16x8 ldg8(const bf16* p) {
    return *reinterpret_cast<const bf16x8*>(p);
}

// ---------------------------------------------------------------------------
// f32 -> bf16 conversion (memory-bound pre-pass). n must be a multiple of 8.
// ---------------------------------------------------------------------------
__global__ __launch_bounds__(256) void cvt(
    const float* __restrict__ s, bf16* __restrict__ d, int n)
{
    const int i = (blockIdx.x * 256 + threadIdx.x) * 8;
    if (i >= n) return;
    f32x4 a = *reinterpret_cast<const f32x4*>(s + i);
    f32x4 b = *reinterpret_cast<const f32x4*>(s + i + 4);
    bf16x8 r;
    #pragma unroll
    for (int j = 0; j < 4; ++j) { r[j] = (bf16)a[j]; r[j + 4] = (bf16)b[j]; }
    *reinterpret_cast<bf16x8*>(d + i) = r;
}

// ---------------------------------------------------------------------------
// m97-style 128x128 GEMM: C = A @ Bm^T.  A:[M_,512] bf16, Bm:[512,512] bf16
// (both K-contiguous). 4 waves in 2x2, 64x64 per wave, BK=64, 32 KB LDS,
// global_load_lds width-16 staging, ds_read_b128 fragments.
// PERM=1: store bf16 permuted into [z][B*H][S][64] (QKV). PERM=0: f32 plain.
// ---------------------------------------------------------------------------
template <int PERM>
__global__ __launch_bounds__(256) void gemm128(
    const bf16* __restrict__ Abase, const bf16* __restrict__ Bbase,
    void* __restrict__ OutBase)
{
    const int z = blockIdx.z;
    const bf16* A  = Abase + (size_t)z * M_ * D_;
    const bf16* Bm = Bbase + (size_t)z * D_ * D_;

    const int tid  = threadIdx.x;
    const int lane = tid & 63;
    const int wave = tid >> 6;
    const int lc = lane & 15;
    const int lg = lane >> 4;
    const int wm = (wave >> 1) * 64;       // wave tile origin in 128x128
    const int wn = (wave & 1) * 64;
    const int nblk = blockIdx.x * 128;
    const int mblk = blockIdx.y * 128;

    __shared__ bf16 As[128 * 64];
    __shared__ bf16 Bs[128 * 64];

    f32x4 acc[4][4] = {};

    for (int k0 = 0; k0 < D_; k0 += 64) {
        __syncthreads();                   // protect LDS from previous readers
        #pragma unroll
        for (int i = 0; i < 4; ++i) {
            const int c   = i * 256 + wave * 64 + lane;  // 16B chunk id (1024 total)
            const int row = c >> 3;                      // 8 chunks per 64-col row
            const int kc  = (c & 7) * 8;
            async16(A + (size_t)(mblk + row) * D_ + k0 + kc,
                    As + (i * 256 + wave * 64) * 8);
            async16(Bm + (size_t)(nblk + row) * D_ + k0 + kc,
                    Bs + (i * 256 + wave * 64) * 8);
        }
        __syncthreads();                   // drains vmcnt (global_load_lds)

        #pragma unroll
        for (int kk = 0; kk < 2; ++kk) {   // two 32-wide MFMA K-steps
            bf16x8 af[4], bfm[4];
            #pragma unroll
            for (int mi = 0; mi < 4; ++mi)
                af[mi] = ldg8(&As[(wm + mi * 16 + lc) * 64 + kk * 32 + lg * 8]);
            #pragma unroll
            for (int ni = 0; ni < 4; ++ni)
                bfm[ni] = ldg8(&Bs[(wn + ni * 16 + lc) * 64 + kk * 32 + lg * 8]);
            #pragma unroll
            for (int mi = 0; mi < 4; ++mi)
                #pragma unroll
                for (int ni = 0; ni < 4; ++ni)
                    acc[mi][ni] = MFMA16(af[mi], bfm[ni], acc[mi][ni]);
        }
    }

    if (PERM) {
        bf16* Y = (bf16*)OutBase + (size_t)z * M_ * D_;   // [B*H][S][64] plane set
        #pragma unroll
        for (int mi = 0; mi < 4; ++mi)
            #pragma unroll
            for (int ni = 0; ni < 4; ++ni)
                #pragma unroll
                for (int r = 0; r < 4; ++r) {
                    const int row = mblk + wm + mi * 16 + lg * 4 + r;  // b*S+s
                    const int col = nblk + wn + ni * 16 + lc;          // h*64+d
                    const size_t oidx =
                        ((((size_t)(row >> 11) * H_ + (col >> 6)) * S_
                          + (row & (S_ - 1))) << 6) + (col & 63);
                    Y[oidx] = (bf16)acc[mi][ni][r];
                }
    } else {
        float* Y = (float*)OutBase;
        #pragma unroll
        for (int mi = 0; mi < 4; ++mi)
            #pragma unroll
            for (int ni = 0; ni < 4; ++ni)
                #pragma unroll
                for (int r = 0; r < 4; ++r) {
                    const int row = mblk + wm + mi * 16 + lg * 4 + r;
                    const int col = nblk + wn + ni * 16 + lc;
                    Y[(size_t)row * D_ + col] = acc[mi][ni][r];
                }
    }
}

// ---------------------------------------------------------------------------
// Causal flash attention over [B*H] planes of [S, DK] bf16.
// Block = 4 waves, 64 q-rows (16/wave). K-tile 64 staged to LDS via
// global_load_lds (shared by all waves); V transposed into LDS.
// ---------------------------------------------------------------------------
__global__ __launch_bounds__(256) void attn(
    const bf16* __restrict__ QKV, bf16* __restrict__ Ctx)
{
    const int bh = blockIdx.y;
    const int b = bh >> 3, h = bh & 7;
    const int q0 = blockIdx.x * 64;
    const size_t plane = (size_t)S_ * DK_;
    const bf16* Q  = QKV + (size_t)bh * plane;
    const bf16* Kp = QKV + (size_t)(B_ * H_) * plane + (size_t)bh * plane;
    const bf16* Vp = QKV + 2 * (size_t)(B_ * H_) * plane + (size_t)bh * plane;

    const int lane = threadIdx.x & 63;
    const int wave = threadIdx.x >> 6;
    const int lc = lane & 15;
    const int lg = lane >> 4;
    const int qw = q0 + wave * 16;

    __shared__ bf16 Ks[64 * 64];      // K tile, row-major (no pad: global_load_lds)
    __shared__ bf16 Vt[64][72];       // V^T tile, +8 pad
    __shared__ bf16 Pl[4][16][72];    // per-wave P round-trip

    bf16x8 qf0 = ldg8(Q + (size_t)(qw + lc) * DK_ + lg * 8);
    bf16x8 qf1 = ldg8(Q + (size_t)(qw + lc) * DK_ + 32 + lg * 8);

    f32x4 accO[4] = {};
    float mi4[4], li[4];
    #pragma unroll
    for (int r = 0; r < 4; ++r) { mi4[r] = -1e30f; li[r] = 0.f; }

    const float scale = 0.125f;       // 1/sqrt(64)
    const float NEG = -1e30f;

    for (int k0 = 0; k0 < q0 + 64; k0 += 64) {
        __syncthreads();              // protect Ks/Vt from previous readers
        // ---- stage K tile via async global->LDS (512 chunks of 16B) --------
        #pragma unroll
        for (int i = 0; i < 2; ++i) {
            const int c   = i * 256 + wave * 64 + lane;
            const int row = c >> 3;
            const int kc  = (c & 7) * 8;
            async16(Kp + (size_t)(k0 + row) * DK_ + kc,
                    Ks + (i * 256 + wave * 64) * 8);
        }
        // ---- transpose-stage V tile ---------------------------------------
        {
            const int kr = threadIdx.x >> 2;
            const int c0 = (threadIdx.x & 3) * 16;
            bf16x8 va = ldg8(Vp + (size_t)(k0 + kr) * DK_ + c0);
            bf16x8 vb = ldg8(Vp + (size_t)(k0 + kr) * DK_ + c0 + 8);
            #pragma unroll
            for (int c = 0; c < 8; ++c) Vt[c0 + c][kr] = va[c];
            #pragma unroll
            for (int c = 0; c < 8; ++c) Vt[c0 + 8 + c][kr] = vb[c];
        }
        __syncthreads();

        // ---- scores S = Q K^T for 16 q x 64 k ------------------------------
        f32x4 sc[4] = {};
        #pragma unroll
        for (int t = 0; t < 4; ++t) {
            bf16x8 b0 = ldg8(&Ks[(t * 16 + lc) * 64 + lg * 8]);
            bf16x8 b1 = ldg8(&Ks[(t * 16 + lc) * 64 + 32 + lg * 8]);
            sc[t] = MFMA16(qf0, b0, sc[t]);
            sc[t] = MFMA16(qf1, b1, sc[t]);
        }

        // ---- online softmax ------------------------------------------------
        float mnew[4], alpha[4];
        #pragma unroll
        for (int r = 0; r < 4; ++r) {
            const int q = qw + lg * 4 + r;
            float mx = mi4[r];
            #pragma unroll
            for (int t = 0; t < 4; ++t) {
                const int kpos = k0 + t * 16 + lc;
                float s = (kpos <= q) ? sc[t][r] * scale : NEG;
                sc[t][r] = s;
                mx = fmaxf(mx, s);
            }
            #pragma unroll
            for (int off = 8; off > 0; off >>= 1)
                mx = fmaxf(mx, __shfl_xor(mx, off, 16));
            mnew[r] = mx;
            alpha[r] = __expf(mi4[r] - mx);
            mi4[r] = mx;
        }
        #pragma unroll
        for (int r = 0; r < 4; ++r) {
            float rs = 0.f;
            #pragma unroll
            for (int t = 0; t < 4; ++t) {
                float p = __expf(sc[t][r] - mnew[r]);
                sc[t][r] = p;
                rs += p;
            }
            #pragma unroll
            for (int off = 8; off > 0; off >>= 1)
                rs += __shfl_xor(rs, off, 16);
            li[r] = li[r] * alpha[r] + rs;
            #pragma unroll
            for (int t = 0; t < 4; ++t) accO[t][r] *= alpha[r];
        }

        // ---- P: C-layout -> A-layout via per-wave LDS ----------------------
        #pragma unroll
        for (int t = 0; t < 4; ++t)
            #pragma unroll
            for (int r = 0; r < 4; ++r)
                Pl[wave][lg * 4 + r][t * 16 + lc] = (bf16)sc[t][r];
        bf16x8 p0 = ldg8(&Pl[wave][lc][lg * 8]);
        bf16x8 p1 = ldg8(&Pl[wave][lc][32 + lg * 8]);

        // ---- O += P V ------------------------------------------------------
        #pragma unroll
        for (int t = 0; t < 4; ++t) {
            bf16x8 v0 = ldg8(&Vt[t * 16 + lc][lg * 8]);
            bf16x8 v1 = ldg8(&Vt[t * 16 + lc][32 + lg * 8]);
            accO[t] = MFMA16(p0, v0, accO[t]);
            accO[t] = MFMA16(p1, v1, accO[t]);
        }
    }

    // ---- epilogue: ctx[b, q, h*64 + d] = O / l -----------------------------
    #pragma unroll
    for (int r = 0; r < 4; ++r) {
        const float rl = 1.0f / li[r];
        #pragma unroll
        for (int t = 0; t < 4; ++t) {
            const int q = qw + lg * 4 + r;
            Ctx[((size_t)b * S_ + q) * D_ + h * 64 + t * 16 + lc]
                = (bf16)(accO[t][r] * rl);
        }
    }
}

extern "C" void kernel_launch(void* const* d_in, const int* in_sizes, int n_in,
                              void* d_out, int out_size, void* d_ws, size_t ws_size,
                              hipStream_t stream)
{
    const float* Xf[3] = { (const float*)d_in[0], (const float*)d_in[1],
                           (const float*)d_in[2] };
    const float* Wf[4] = { (const float*)d_in[3], (const float*)d_in[4],
                           (const float*)d_in[5], (const float*)d_in[6] };
    float* out = (float*)d_out;

    bf16* Xb  = (bf16*)d_ws;                          // [3][M_][D_]
    bf16* Wb  = Xb + (size_t)3 * M_ * D_;             // [4][D_][D_]
    bf16* qkv = Wb + (size_t)4 * D_ * D_;             // [3][B*H][S][64]
    bf16* ctx = qkv + (size_t)3 * M_ * D_;            // [M_][D_]

    for (int i = 0; i < 3; ++i)
        cvt<<<M_ * D_ / 2048, 256, 0, stream>>>(Xf[i], Xb + (size_t)i * M_ * D_, M_ * D_);
    for (int i = 0; i < 4; ++i)
        cvt<<<D_ * D_ / 2048, 256, 0, stream>>>(Wf[i], Wb + (size_t)i * D_ * D_, D_ * D_);

    gemm128<1><<<dim3(D_ / 128, M_ / 128, 3), 256, 0, stream>>>(Xb, Wb, qkv);
    attn<<<dim3(S_ / 64, B_ * H_), 256, 0, stream>>>(qkv, ctx);
    gemm128<0><<<dim3(D_ / 128, M_ / 128, 1), 256, 0, stream>>>(
        ctx, Wb + (size_t)3 * D_ * D_, out);
}

// Round 4
// 239.057 us; speedup vs baseline: 2.1474x; 1.2685x over previous
//
#include <hip/hip_runtime.h>
#include <hip/hip_bf16.h>
#include <math.h>

#define B_  4
#define S_  2048
#define D_  512
#define H_  8
#define DK_ 64
#define M_  (B_ * S_)   // 8192

using bf16   = __bf16;
using bf16x4 = __bf16 __attribute__((ext_vector_type(4)));
using bf16x8 = __bf16 __attribute__((ext_vector_type(8)));
using f32x4  = float __attribute__((ext_vector_type(4)));

#define MFMA16(a, b, c) __builtin_amdgcn_mfma_f32_16x16x32_bf16((a), (b), (c), 0, 0, 0)

typedef __attribute__((address_space(3))) void       lds_void;
typedef const __attribute__((address_space(1))) void gbl_void;

__device__ __forceinline__ void async16(const bf16* g, bf16* lds) {
    __builtin_amdgcn_global_load_lds((gbl_void*)g, (lds_void*)lds, 16, 0, 0);
}

__device__ __forceinline__ bf16x8 ldg8(const bf16* p) {
    return *reinterpret_cast<const bf16x8*>(p);
}

// ---------------------------------------------------------------------------
// Fused f32->bf16 for all 7 tensors (dest is one contiguous ws run).
// Concatenated span: 3 x 2^22 (X) then 4 x 2^18 (W). Total 13631488 elems.
// ---------------------------------------------------------------------------
__global__ __launch_bounds__(256) void cvt_all(
    const float* __restrict__ x0, const float* __restrict__ x1, const float* __restrict__ x2,
    const float* __restrict__ w0, const float* __restrict__ w1,
    const float* __restrict__ w2, const float* __restrict__ w3,
    bf16* __restrict__ dst)
{
    const size_t i = ((size_t)blockIdx.x * 256 + threadIdx.x) * 8;
    const float* src;
    size_t off;
    if (i < (size_t)3 << 22) {
        const int seg = (int)(i >> 22);
        off = i & (((size_t)1 << 22) - 1);
        src = (seg == 0) ? x0 : (seg == 1) ? x1 : x2;
    } else {
        const size_t j = i - ((size_t)3 << 22);
        const int seg = (int)(j >> 18);
        off = j & (((size_t)1 << 18) - 1);
        src = (seg == 0) ? w0 : (seg == 1) ? w1 : (seg == 2) ? w2 : w3;
    }
    f32x4 a = *reinterpret_cast<const f32x4*>(src + off);
    f32x4 b = *reinterpret_cast<const f32x4*>(src + off + 4);
    bf16x8 r;
    #pragma unroll
    for (int j = 0; j < 4; ++j) { r[j] = (bf16)a[j]; r[j + 4] = (bf16)b[j]; }
    *reinterpret_cast<bf16x8*>(dst + i) = r;
}

// ---------------------------------------------------------------------------
// m97-style 128x128 GEMM: C = A @ Bm^T (both K-contiguous bf16).
// PERM=1: z in {0,1,2}; z<2 store [z][bh][s][64]; z==2 store V^T [bh][d][s].
// PERM=0: plain f32 [M_,D_] store.
// ---------------------------------------------------------------------------
template <int PERM>
__global__ __launch_bounds__(256) void gemm128(
    const bf16* __restrict__ Abase, const bf16* __restrict__ Bbase,
    void* __restrict__ OutBase)
{
    const int z = blockIdx.z;
    const bf16* A  = Abase + (size_t)z * M_ * D_;
    const bf16* Bm = Bbase + (size_t)z * D_ * D_;

    const int lane = threadIdx.x & 63;
    const int wave = threadIdx.x >> 6;
    const int lc = lane & 15;
    const int lg = lane >> 4;
    const int wm = (wave >> 1) * 64;
    const int wn = (wave & 1) * 64;
    const int nblk = blockIdx.x * 128;
    const int mblk = blockIdx.y * 128;

    __shared__ bf16 As[128 * 64];
    __shared__ bf16 Bs[128 * 64];

    f32x4 acc[4][4] = {};

    for (int k0 = 0; k0 < D_; k0 += 64) {
        __syncthreads();
        #pragma unroll
        for (int i = 0; i < 4; ++i) {
            const int c   = i * 256 + wave * 64 + lane;
            const int row = c >> 3;
            const int kc  = (c & 7) * 8;
            async16(A + (size_t)(mblk + row) * D_ + k0 + kc,
                    As + (i * 256 + wave * 64) * 8);
            async16(Bm + (size_t)(nblk + row) * D_ + k0 + kc,
                    Bs + (i * 256 + wave * 64) * 8);
        }
        __syncthreads();

        #pragma unroll
        for (int kk = 0; kk < 2; ++kk) {
            bf16x8 af[4], bfm[4];
            #pragma unroll
            for (int mi = 0; mi < 4; ++mi)
                af[mi] = ldg8(&As[(wm + mi * 16 + lc) * 64 + kk * 32 + lg * 8]);
            #pragma unroll
            for (int ni = 0; ni < 4; ++ni)
                bfm[ni] = ldg8(&Bs[(wn + ni * 16 + lc) * 64 + kk * 32 + lg * 8]);
            #pragma unroll
            for (int mi = 0; mi < 4; ++mi)
                #pragma unroll
                for (int ni = 0; ni < 4; ++ni)
                    acc[mi][ni] = MFMA16(af[mi], bfm[ni], acc[mi][ni]);
        }
    }

    if (PERM) {
        bf16* Y = (bf16*)OutBase + (size_t)z * M_ * D_;
        if (z == 2) {
            // V^T store: [bh][d][s], 8B packed along s
            #pragma unroll
            for (int mi = 0; mi < 4; ++mi)
                #pragma unroll
                for (int ni = 0; ni < 4; ++ni) {
                    const int s0  = mblk + wm + mi * 16 + lg * 4;
                    const int col = nblk + wn + ni * 16 + lc;
                    bf16x4 v;
                    #pragma unroll
                    for (int r = 0; r < 4; ++r) v[r] = (bf16)acc[mi][ni][r];
                    const size_t oidx =
                        ((((size_t)(s0 >> 11)) * H_ + (col >> 6)) << 17)
                        + (size_t)(col & 63) * S_ + (s0 & (S_ - 1));
                    *reinterpret_cast<bf16x4*>(&Y[oidx]) = v;
                }
        } else {
            #pragma unroll
            for (int mi = 0; mi < 4; ++mi)
                #pragma unroll
                for (int ni = 0; ni < 4; ++ni)
                    #pragma unroll
                    for (int r = 0; r < 4; ++r) {
                        const int row = mblk + wm + mi * 16 + lg * 4 + r;
                        const int col = nblk + wn + ni * 16 + lc;
                        const size_t oidx =
                            ((((size_t)(row >> 11) * H_ + (col >> 6)) * S_
                              + (row & (S_ - 1))) << 6) + (col & 63);
                        Y[oidx] = (bf16)acc[mi][ni][r];
                    }
        }
    } else {
        float* Y = (float*)OutBase;
        #pragma unroll
        for (int mi = 0; mi < 4; ++mi)
            #pragma unroll
            for (int ni = 0; ni < 4; ++ni)
                #pragma unroll
                for (int r = 0; r < 4; ++r) {
                    const int row = mblk + wm + mi * 16 + lg * 4 + r;
                    const int col = nblk + wn + ni * 16 + lc;
                    Y[(size_t)row * D_ + col] = acc[mi][ni][r];
                }
    }
}

// ---------------------------------------------------------------------------
// Causal flash attention, operand-swapped (scores transposed: col=q, row=k).
// Q:[bh][s][64], K:[bh][s][64], V^T:[bh][d][s]. Block = 4 waves, 64 q-rows.
// Per lane: single q = qw + (lane&15); m/l scalar per lane.
// ---------------------------------------------------------------------------
__global__ __launch_bounds__(256) void attn(
    const bf16* __restrict__ QKV, bf16* __restrict__ Ctx)
{
    const int bh = blockIdx.y;
    const int b = bh >> 3, h = bh & 7;
    const int q0 = blockIdx.x * 64;
    const size_t plane = (size_t)S_ * DK_;
    const bf16* Q  = QKV + (size_t)bh * plane;
    const bf16* Kp = QKV + (size_t)(B_ * H_) * plane + (size_t)bh * plane;
    const bf16* Vt = QKV + 2 * (size_t)(B_ * H_) * plane + (size_t)bh * plane;

    const int lane = threadIdx.x & 63;
    const int wave = threadIdx.x >> 6;
    const int lc = lane & 15;
    const int lg = lane >> 4;
    const int qw = q0 + wave * 16;
    const int q  = qw + lc;

    __shared__ bf16 Ks[64 * 64];      // K tile [k][d]
    __shared__ bf16 Vs[64 * 64];      // V^T tile [d][k]
    __shared__ bf16 Pl[4][16][72];    // per-wave P: [q][k], +8 pad

    // Q B-frag (n=q=lc, k=lg*8+j), pre-scaled by 1/8 (exact pow2 in bf16)
    bf16x8 qf0 = ldg8(Q + (size_t)q * DK_ + lg * 8);
    bf16x8 qf1 = ldg8(Q + (size_t)q * DK_ + 32 + lg * 8);
    #pragma unroll
    for (int j = 0; j < 8; ++j) {
        qf0[j] = (bf16)((float)qf0[j] * 0.125f);
        qf1[j] = (bf16)((float)qf1[j] * 0.125f);
    }

    f32x4 accO[4] = {};               // O^T tiles: col=q=lc, row=d=t*16+lg*4+r
    float mi = -1e30f, li = 0.f;

    for (int k0 = 0; k0 < q0 + 64; k0 += 64) {
        __syncthreads();
        #pragma unroll
        for (int i = 0; i < 2; ++i) {
            const int c   = i * 256 + wave * 64 + lane;
            const int row = c >> 3;
            const int kc  = (c & 7) * 8;
            async16(Kp + (size_t)(k0 + row) * DK_ + kc, Ks + (i * 256 + wave * 64) * 8);
            async16(Vt + (size_t)row * S_ + k0 + kc,    Vs + (i * 256 + wave * 64) * 8);
        }
        __syncthreads();

        if (k0 < qw + 16) {           // wave-uniform: skip fully-masked tiles
            // ---- S^T = K Q^T: st[t] C-layout col=q=lc, row=k=t*16+lg*4+r ---
            f32x4 st[4];
            #pragma unroll
            for (int t = 0; t < 4; ++t) {
                bf16x8 kf0 = ldg8(&Ks[(t * 16 + lc) * 64 + lg * 8]);
                bf16x8 kf1 = ldg8(&Ks[(t * 16 + lc) * 64 + 32 + lg * 8]);
                f32x4 zz = {};
                zz = MFMA16(kf0, qf0, zz);
                st[t] = MFMA16(kf1, qf1, zz);
            }

            // ---- mask (diagonal tiles only) + online softmax ---------------
            float mx = mi;
            if (k0 + 64 > qw) {
                #pragma unroll
                for (int t = 0; t < 4; ++t)
                    #pragma unroll
                    for (int r = 0; r < 4; ++r) {
                        const int kpos = k0 + t * 16 + lg * 4 + r;
                        float s = (kpos <= q) ? st[t][r] : -1e30f;
                        st[t][r] = s;
                        mx = fmaxf(mx, s);
                    }
            } else {
                #pragma unroll
                for (int t = 0; t < 4; ++t)
                    #pragma unroll
                    for (int r = 0; r < 4; ++r) mx = fmaxf(mx, st[t][r]);
            }
            mx = fmaxf(mx, __shfl_xor(mx, 16));
            mx = fmaxf(mx, __shfl_xor(mx, 32));

            const float alpha = __expf(mi - mx);
            float rs = 0.f;
            #pragma unroll
            for (int t = 0; t < 4; ++t)
                #pragma unroll
                for (int r = 0; r < 4; ++r) {
                    const float p = __expf(st[t][r] - mx);
                    st[t][r] = p;
                    rs += p;
                }
            rs += __shfl_xor(rs, 16);
            rs += __shfl_xor(rs, 32);
            li = li * alpha + rs;
            mi = mx;
            #pragma unroll
            for (int t = 0; t < 4; ++t)
                #pragma unroll
                for (int r = 0; r < 4; ++r) accO[t][r] *= alpha;

            // ---- P to LDS in [q][k] (B-frag layout), packed b64 ------------
            #pragma unroll
            for (int t = 0; t < 4; ++t) {
                bf16x4 pv;
                #pragma unroll
                for (int r = 0; r < 4; ++r) pv[r] = (bf16)st[t][r];
                *reinterpret_cast<bf16x4*>(&Pl[wave][lc][t * 16 + lg * 4]) = pv;
            }
            bf16x8 p0 = ldg8(&Pl[wave][lc][lg * 8]);
            bf16x8 p1 = ldg8(&Pl[wave][lc][32 + lg * 8]);

            // ---- O^T += V^T P: A=V^T-frag (m=d), B=P-frag (n=q) ------------
            #pragma unroll
            for (int t = 0; t < 4; ++t) {
                bf16x8 v0 = ldg8(&Vs[(t * 16 + lc) * 64 + lg * 8]);
                bf16x8 v1 = ldg8(&Vs[(t * 16 + lc) * 64 + 32 + lg * 8]);
                accO[t] = MFMA16(v0, p0, accO[t]);
                accO[t] = MFMA16(v1, p1, accO[t]);
            }
        }
    }

    // ---- epilogue: ctx[b][q][h*64+d] = O^T/l, packed b64 along d -----------
    const float rl = 1.0f / li;
    #pragma unroll
    for (int t = 0; t < 4; ++t) {
        bf16x4 ov;
        #pragma unroll
        for (int r = 0; r < 4; ++r) ov[r] = (bf16)(accO[t][r] * rl);
        const int d = t * 16 + lg * 4;
        *reinterpret_cast<bf16x4*>(&Ctx[((size_t)b * S_ + q) * D_ + h * 64 + d]) = ov;
    }
}

extern "C" void kernel_launch(void* const* d_in, const int* in_sizes, int n_in,
                              void* d_out, int out_size, void* d_ws, size_t ws_size,
                              hipStream_t stream)
{
    float* out = (float*)d_out;

    bf16* Xb  = (bf16*)d_ws;                          // [3][M_][D_]
    bf16* Wb  = Xb + (size_t)3 * M_ * D_;             // [4][D_][D_]
    bf16* qkv = Wb + (size_t)4 * D_ * D_;             // [3][32][...]
    bf16* ctx = qkv + (size_t)3 * M_ * D_;            // [M_][D_]

    cvt_all<<<6656, 256, 0, stream>>>(
        (const float*)d_in[0], (const float*)d_in[1], (const float*)d_in[2],
        (const float*)d_in[3], (const float*)d_in[4], (const float*)d_in[5],
        (const float*)d_in[6], Xb);

    gemm128<1><<<dim3(D_ / 128, M_ / 128, 3), 256, 0, stream>>>(Xb, Wb, qkv);
    attn<<<dim3(S_ / 64, B_ * H_), 256, 0, stream>>>(qkv, ctx);
    gemm128<0><<<dim3(D_ / 128, M_ / 128, 1), 256, 0, stream>>>(
        ctx, Wb + (size_t)3 * D_ * D_, out);
}

// Round 5
// 227.939 us; speedup vs baseline: 2.2521x; 1.0488x over previous
//
#include <hip/hip_runtime.h>
#include <hip/hip_bf16.h>
#include <math.h>

#define B_  4
#define S_  2048
#define D_  512
#define H_  8
#define DK_ 64
#define M_  (B_ * S_)   // 8192

using bf16   = __bf16;
using bf16x4 = __bf16 __attribute__((ext_vector_type(4)));
using bf16x8 = __bf16 __attribute__((ext_vector_type(8)));
using f32x4  = float __attribute__((ext_vector_type(4)));

#define MFMA16(a, b, c) __builtin_amdgcn_mfma_f32_16x16x32_bf16((a), (b), (c), 0, 0, 0)

#if __has_builtin(__builtin_amdgcn_exp2f)
#define EXP2(x) __builtin_amdgcn_exp2f(x)
#else
#define EXP2(x) exp2f(x)
#endif

typedef __attribute__((address_space(3))) void       lds_void;
typedef const __attribute__((address_space(1))) void gbl_void;

__device__ __forceinline__ void async16(const bf16* g, bf16* lds) {
    __builtin_amdgcn_global_load_lds((gbl_void*)g, (lds_void*)lds, 16, 0, 0);
}

__device__ __forceinline__ bf16x8 ldg8(const bf16* p) {
    return *reinterpret_cast<const bf16x8*>(p);
}

// ---------------------------------------------------------------------------
// Fused f32->bf16 for all 7 tensors. Span: 3 x 2^22 (X) then 4 x 2^18 (W).
// ---------------------------------------------------------------------------
__global__ __launch_bounds__(256) void cvt_all(
    const float* __restrict__ x0, const float* __restrict__ x1, const float* __restrict__ x2,
    const float* __restrict__ w0, const float* __restrict__ w1,
    const float* __restrict__ w2, const float* __restrict__ w3,
    bf16* __restrict__ dst)
{
    const size_t i = ((size_t)blockIdx.x * 256 + threadIdx.x) * 8;
    const float* src;
    size_t off;
    if (i < (size_t)3 << 22) {
        const int seg = (int)(i >> 22);
        off = i & (((size_t)1 << 22) - 1);
        src = (seg == 0) ? x0 : (seg == 1) ? x1 : x2;
    } else {
        const size_t j = i - ((size_t)3 << 22);
        const int seg = (int)(j >> 18);
        off = j & (((size_t)1 << 18) - 1);
        src = (seg == 0) ? w0 : (seg == 1) ? w1 : (seg == 2) ? w2 : w3;
    }
    f32x4 a = *reinterpret_cast<const f32x4*>(src + off);
    f32x4 b = *reinterpret_cast<const f32x4*>(src + off + 4);
    bf16x8 r;
    #pragma unroll
    for (int j = 0; j < 4; ++j) { r[j] = (bf16)a[j]; r[j + 4] = (bf16)b[j]; }
    *reinterpret_cast<bf16x8*>(dst + i) = r;
}

// ---------------------------------------------------------------------------
// 128x128 GEMM: C = A @ Bm^T (both K-contiguous bf16), fragment-major LDS
// (chunk pos = kk*512 + (row>>4)*64 + (kc&3)*16 + (row&15)) so every
// ds_read_b128 is lane-coalesced (zero bank conflicts).
// PERM=1: z in {0,1,2}; z<2 store [z][bh][s][64]; z==2 store V^T [bh][d][s].
// PERM=0: plain f32 [M_,D_] store.
// ---------------------------------------------------------------------------
template <int PERM>
__global__ __launch_bounds__(256) void gemm128(
    const bf16* __restrict__ Abase, const bf16* __restrict__ Bbase,
    void* __restrict__ OutBase)
{
    const int z = blockIdx.z;
    const bf16* A  = Abase + (size_t)z * M_ * D_;
    const bf16* Bm = Bbase + (size_t)z * D_ * D_;

    const int lane = threadIdx.x & 63;
    const int wave = threadIdx.x >> 6;
    const int lc = lane & 15;
    const int lg = lane >> 4;
    const int wm = (wave >> 1) * 64;
    const int wn = (wave & 1) * 64;
    const int wmt = (wave >> 1) * 4;       // row-tile base (16-row units)
    const int wnt = (wave & 1) * 4;
    const int nblk = blockIdx.x * 128;
    const int mblk = blockIdx.y * 128;

    __shared__ bf16 As[128 * 64];
    __shared__ bf16 Bs[128 * 64];

    f32x4 acc[4][4] = {};

    for (int k0 = 0; k0 < D_; k0 += 64) {
        __syncthreads();
        #pragma unroll
        for (int i = 0; i < 4; ++i) {
            const int g   = i * 4 + wave;          // 0..15
            const int row = (g & 7) * 16 + lc;
            const int kc  = (g >> 3) * 4 + lg;
            async16(A + (size_t)(mblk + row) * D_ + k0 + kc * 8,
                    As + (i * 256 + wave * 64) * 8);
            async16(Bm + (size_t)(nblk + row) * D_ + k0 + kc * 8,
                    Bs + (i * 256 + wave * 64) * 8);
        }
        __syncthreads();

        #pragma unroll
        for (int kk = 0; kk < 2; ++kk) {
            bf16x8 af[4], bfm[4];
            #pragma unroll
            for (int mi = 0; mi < 4; ++mi)
                af[mi] = ldg8(&As[(kk * 512 + (wmt + mi) * 64 + lane) * 8]);
            #pragma unroll
            for (int ni = 0; ni < 4; ++ni)
                bfm[ni] = ldg8(&Bs[(kk * 512 + (wnt + ni) * 64 + lane) * 8]);
            #pragma unroll
            for (int mi = 0; mi < 4; ++mi)
                #pragma unroll
                for (int ni = 0; ni < 4; ++ni)
                    acc[mi][ni] = MFMA16(af[mi], bfm[ni], acc[mi][ni]);
        }
    }

    if (PERM) {
        bf16* Y = (bf16*)OutBase + (size_t)z * M_ * D_;
        if (z == 2) {
            #pragma unroll
            for (int mi = 0; mi < 4; ++mi)
                #pragma unroll
                for (int ni = 0; ni < 4; ++ni) {
                    const int s0  = mblk + wm + mi * 16 + lg * 4;
                    const int col = nblk + wn + ni * 16 + lc;
                    bf16x4 v;
                    #pragma unroll
                    for (int r = 0; r < 4; ++r) v[r] = (bf16)acc[mi][ni][r];
                    const size_t oidx =
                        ((((size_t)(s0 >> 11)) * H_ + (col >> 6)) << 17)
                        + (size_t)(col & 63) * S_ + (s0 & (S_ - 1));
                    *reinterpret_cast<bf16x4*>(&Y[oidx]) = v;
                }
        } else {
            #pragma unroll
            for (int mi = 0; mi < 4; ++mi)
                #pragma unroll
                for (int ni = 0; ni < 4; ++ni)
                    #pragma unroll
                    for (int r = 0; r < 4; ++r) {
                        const int row = mblk + wm + mi * 16 + lg * 4 + r;
                        const int col = nblk + wn + ni * 16 + lc;
                        const size_t oidx =
                            ((((size_t)(row >> 11) * H_ + (col >> 6)) * S_
                              + (row & (S_ - 1))) << 6) + (col & 63);
                        Y[oidx] = (bf16)acc[mi][ni][r];
                    }
        }
    } else {
        float* Y = (float*)OutBase;
        #pragma unroll
        for (int mi = 0; mi < 4; ++mi)
            #pragma unroll
            for (int ni = 0; ni < 4; ++ni)
                #pragma unroll
                for (int r = 0; r < 4; ++r) {
                    const int row = mblk + wm + mi * 16 + lg * 4 + r;
                    const int col = nblk + wn + ni * 16 + lc;
                    Y[(size_t)row * D_ + col] = acc[mi][ni][r];
                }
    }
}

// ---------------------------------------------------------------------------
// Causal flash attention, operand-swapped, fragment-major LDS, double-buffered
// K/V staging. Q:[bh][s][64], K:[bh][s][64], V^T:[bh][d][s].
// Grid = 1024 blocks = 4/CU (40 KB LDS) -> fully co-resident.
// ---------------------------------------------------------------------------
__global__ __launch_bounds__(256) void attn(
    const bf16* __restrict__ QKV, bf16* __restrict__ Ctx)
{
    const int bh = blockIdx.y;
    const int b = bh >> 3, h = bh & 7;
    const int q0 = blockIdx.x * 64;
    const size_t plane = (size_t)S_ * DK_;
    const bf16* Q  = QKV + (size_t)bh * plane;
    const bf16* Kp = QKV + (size_t)(B_ * H_) * plane + (size_t)bh * plane;
    const bf16* Vt = QKV + 2 * (size_t)(B_ * H_) * plane + (size_t)bh * plane;

    const int lane = threadIdx.x & 63;
    const int wave = threadIdx.x >> 6;
    const int lc = lane & 15;
    const int lg = lane >> 4;
    const int qw = q0 + wave * 16;
    const int q  = qw + lc;

    __shared__ bf16 Ks[2][64 * 64];   // frag-major: chunk = kk*256 + t*64 + lane
    __shared__ bf16 Vs[2][64 * 64];   // same layout (rows = d)
    __shared__ bf16 Pw[4][128 * 8];   // per-wave P, chunk = kc*16 + q

    // Q B-frag (n=q, k=lg*8+j), pre-scaled by exact 1/8
    bf16x8 qf0 = ldg8(Q + (size_t)q * DK_ + lg * 8);
    bf16x8 qf1 = ldg8(Q + (size_t)q * DK_ + 32 + lg * 8);
    #pragma unroll
    for (int j = 0; j < 8; ++j) {
        qf0[j] = (bf16)((float)qf0[j] * 0.125f);
        qf1[j] = (bf16)((float)qf1[j] * 0.125f);
    }

    f32x4 accO[4] = {};               // O^T: col=q=lc, row=d=t*16+lg*4+r
    float mi = -1e30f, li = 0.f;
    const float L2E = 1.442695041f;

    const int srow = wave * 16 + lc;  // staging row (this wave's chunk group)
    const int ntiles = q0 / 64 + 1;

    // prologue: stage tile 0 into buffer 0
    #pragma unroll
    for (int i = 0; i < 2; ++i) {
        const int kc = i * 4 + lg;
        async16(Kp + (size_t)srow * DK_ + kc * 8,      Ks[0] + (i * 256 + wave * 64) * 8);
        async16(Vt + (size_t)srow * S_ + kc * 8,       Vs[0] + (i * 256 + wave * 64) * 8);
    }

    for (int j = 0; j < ntiles; ++j) {
        __syncthreads();              // tile j staged; buf j-1 readers done
        if (j + 1 < ntiles) {
            const int kn = (j + 1) * 64;
            bf16* kd = Ks[(j + 1) & 1];
            bf16* vd = Vs[(j + 1) & 1];
            #pragma unroll
            for (int i = 0; i < 2; ++i) {
                const int kc = i * 4 + lg;
                async16(Kp + (size_t)(kn + srow) * DK_ + kc * 8, kd + (i * 256 + wave * 64) * 8);
                async16(Vt + (size_t)srow * S_ + kn + kc * 8,    vd + (i * 256 + wave * 64) * 8);
            }
        }
        const int k0 = j * 64;
        if (k0 >= qw + 16) continue;  // wave-uniform: fully masked for this wave
        const bf16* ks = Ks[j & 1];
        const bf16* vs = Vs[j & 1];

        // ---- S^T = K Q^T (C: col=q=lc, row=k=t*16+lg*4+r) ------------------
        f32x4 st[4];
        #pragma unroll
        for (int t = 0; t < 4; ++t) {
            bf16x8 kf0 = ldg8(&ks[(t * 64 + lane) * 8]);
            bf16x8 kf1 = ldg8(&ks[(256 + t * 64 + lane) * 8]);
            f32x4 zz = {};
            zz = MFMA16(kf0, qf0, zz);
            st[t] = MFMA16(kf1, qf1, zz);
        }

        // ---- online softmax in log2 domain ---------------------------------
        float mx = mi;
        if (k0 + 64 > qw) {           // diagonal tile for this wave: mask
            #pragma unroll
            for (int t = 0; t < 4; ++t)
                #pragma unroll
                for (int r = 0; r < 4; ++r) {
                    const int kpos = k0 + t * 16 + lg * 4 + r;
                    const float s = (kpos <= q) ? st[t][r] * L2E : -1e30f;
                    st[t][r] = s;
                    mx = fmaxf(mx, s);
                }
        } else {
            #pragma unroll
            for (int t = 0; t < 4; ++t)
                #pragma unroll
                for (int r = 0; r < 4; ++r) {
                    const float s = st[t][r] * L2E;
                    st[t][r] = s;
                    mx = fmaxf(mx, s);
                }
        }
        mx = fmaxf(mx, __shfl_xor(mx, 16));
        mx = fmaxf(mx, __shfl_xor(mx, 32));

        const float alpha = EXP2(mi - mx);
        mi = mx;
        float rs = 0.f;
        #pragma unroll
        for (int t = 0; t < 4; ++t)
            #pragma unroll
            for (int r = 0; r < 4; ++r) {
                const float p = EXP2(st[t][r] - mx);
                st[t][r] = p;
                rs += p;
            }
        rs += __shfl_xor(rs, 16);
        rs += __shfl_xor(rs, 32);
        li = li * alpha + rs;
        #pragma unroll
        for (int t = 0; t < 4; ++t)
            #pragma unroll
            for (int r = 0; r < 4; ++r) accO[t][r] *= alpha;

        // ---- P to per-wave LDS (chunk-major [kc][q]) -----------------------
        bf16* Pp = &Pw[wave][0];
        #pragma unroll
        for (int t = 0; t < 4; ++t) {
            bf16x4 pv;
            #pragma unroll
            for (int r = 0; r < 4; ++r) pv[r] = (bf16)st[t][r];
            *reinterpret_cast<bf16x4*>(
                &Pp[((2 * t + (lg >> 1)) * 16 + lc) * 8 + (lg & 1) * 4]) = pv;
        }
        bf16x8 p0 = ldg8(&Pp[lane * 8]);
        bf16x8 p1 = ldg8(&Pp[(64 + lane) * 8]);

        // ---- O^T += V^T P --------------------------------------------------
        #pragma unroll
        for (int t = 0; t < 4; ++t) {
            bf16x8 v0 = ldg8(&vs[(t * 64 + lane) * 8]);
            bf16x8 v1 = ldg8(&vs[(256 + t * 64 + lane) * 8]);
            accO[t] = MFMA16(v0, p0, accO[t]);
            accO[t] = MFMA16(v1, p1, accO[t]);
        }
    }

    // ---- epilogue ----------------------------------------------------------
    const float rl = 1.0f / li;
    #pragma unroll
    for (int t = 0; t < 4; ++t) {
        bf16x4 ov;
        #pragma unroll
        for (int r = 0; r < 4; ++r) ov[r] = (bf16)(accO[t][r] * rl);
        const int d = t * 16 + lg * 4;
        *reinterpret_cast<bf16x4*>(&Ctx[((size_t)b * S_ + q) * D_ + h * 64 + d]) = ov;
    }
}

extern "C" void kernel_launch(void* const* d_in, const int* in_sizes, int n_in,
                              void* d_out, int out_size, void* d_ws, size_t ws_size,
                              hipStream_t stream)
{
    float* out = (float*)d_out;

    bf16* Xb  = (bf16*)d_ws;                          // [3][M_][D_]
    bf16* Wb  = Xb + (size_t)3 * M_ * D_;             // [4][D_][D_]
    bf16* qkv = Wb + (size_t)4 * D_ * D_;             // Q,K [bh][s][64]; V^T [bh][d][s]
    bf16* ctx = qkv + (size_t)3 * M_ * D_;            // [M_][D_]

    cvt_all<<<6656, 256, 0, stream>>>(
        (const float*)d_in[0], (const float*)d_in[1], (const float*)d_in[2],
        (const float*)d_in[3], (const float*)d_in[4], (const float*)d_in[5],
        (const float*)d_in[6], Xb);

    gemm128<1><<<dim3(D_ / 128, M_ / 128, 3), 256, 0, stream>>>(Xb, Wb, qkv);
    attn<<<dim3(S_ / 64, B_ * H_), 256, 0, stream>>>(qkv, ctx);
    gemm128<0><<<dim3(D_ / 128, M_ / 128, 1), 256, 0, stream>>>(
        ctx, Wb + (size_t)3 * D_ * D_, out);
}

// Round 6
// 217.508 us; speedup vs baseline: 2.3601x; 1.0480x over previous
//
#include <hip/hip_runtime.h>
#include <hip/hip_bf16.h>
#include <math.h>

#define B_  4
#define S_  2048
#define D_  512
#define H_  8
#define DK_ 64
#define M_  (B_ * S_)   // 8192

using bf16   = __bf16;
using bf16x4 = __bf16 __attribute__((ext_vector_type(4)));
using bf16x8 = __bf16 __attribute__((ext_vector_type(8)));
using f32x4  = float __attribute__((ext_vector_type(4)));

#define MFMA16(a, b, c) __builtin_amdgcn_mfma_f32_16x16x32_bf16((a), (b), (c), 0, 0, 0)
#define EXP2(x) exp2f(x)

typedef __attribute__((address_space(3))) void       lds_void;
typedef const __attribute__((address_space(1))) void gbl_void;

__device__ __forceinline__ void async16(const bf16* g, bf16* lds) {
    __builtin_amdgcn_global_load_lds((gbl_void*)g, (lds_void*)lds, 16, 0, 0);
}

__device__ __forceinline__ bf16x8 ldg8(const bf16* p) {
    return *reinterpret_cast<const bf16x8*>(p);
}

// ---------------------------------------------------------------------------
// Fused f32->bf16 for all 7 tensors. Span: 3 x 2^22 (X) then 4 x 2^18 (W).
// ---------------------------------------------------------------------------
__global__ __launch_bounds__(256) void cvt_all(
    const float* __restrict__ x0, const float* __restrict__ x1, const float* __restrict__ x2,
    const float* __restrict__ w0, const float* __restrict__ w1,
    const float* __restrict__ w2, const float* __restrict__ w3,
    bf16* __restrict__ dst)
{
    const size_t i = ((size_t)blockIdx.x * 256 + threadIdx.x) * 8;
    const float* src;
    size_t off;
    if (i < (size_t)3 << 22) {
        const int seg = (int)(i >> 22);
        off = i & (((size_t)1 << 22) - 1);
        src = (seg == 0) ? x0 : (seg == 1) ? x1 : x2;
    } else {
        const size_t j = i - ((size_t)3 << 22);
        const int seg = (int)(j >> 18);
        off = j & (((size_t)1 << 18) - 1);
        src = (seg == 0) ? w0 : (seg == 1) ? w1 : (seg == 2) ? w2 : w3;
    }
    f32x4 a = *reinterpret_cast<const f32x4*>(src + off);
    f32x4 b = *reinterpret_cast<const f32x4*>(src + off + 4);
    bf16x8 r;
    #pragma unroll
    for (int j = 0; j < 4; ++j) { r[j] = (bf16)a[j]; r[j + 4] = (bf16)b[j]; }
    *reinterpret_cast<bf16x8*>(dst + i) = r;
}

// ---------------------------------------------------------------------------
// 128x128 GEMM over K=512, fragment-major LDS (zero-conflict ds_read_b128).
// MODE 0: z in {0,1,2} -> qkv. z<2 operand-SWAPPED (A=W m=d, B=X n=s) so the
//   C-regs run along d -> packed bf16x4 stores into [z][bh][s][64]; z==0 also
//   folds the softmax scale 0.125*log2e. z==2 unswapped -> packed V^T store.
// MODE 1: out projection, swapped, f32x4 stores to d_out.
// ---------------------------------------------------------------------------
template <int MODE>
__global__ __launch_bounds__(256) void gemm_proj(
    const bf16* __restrict__ Xbase, const bf16* __restrict__ Wbase,
    void* __restrict__ OutBase)
{
    const int z = (MODE == 0) ? blockIdx.z : 3;
    const bf16* X  = Xbase + ((MODE == 0) ? (size_t)z * M_ * D_ : 0);
    const bf16* Wm = Wbase + (size_t)z * D_ * D_;

    const int lane = threadIdx.x & 63;
    const int wave = threadIdx.x >> 6;
    const int lc = lane & 15;
    const int lg = lane >> 4;
    const int ta = (wave >> 1) * 4;        // m-operand tile base (16-row units)
    const int tb = (wave & 1) * 4;         // n-operand tile base
    const int wblk = blockIdx.x * 128;     // W rows (d)
    const int xblk = blockIdx.y * 128;     // X rows (s)
    const bool swapped = (MODE == 1) || (z < 2);

    __shared__ bf16 As[128 * 64];          // X rows
    __shared__ bf16 Bs[128 * 64];          // W rows

    f32x4 acc[4][4] = {};

    for (int k0 = 0; k0 < D_; k0 += 64) {
        __syncthreads();
        #pragma unroll
        for (int i = 0; i < 4; ++i) {
            const int g   = i * 4 + wave;
            const int row = (g & 7) * 16 + lc;
            const int kc  = (g >> 3) * 4 + lg;
            async16(X  + (size_t)(xblk + row) * D_ + k0 + kc * 8,
                    As + (i * 256 + wave * 64) * 8);
            async16(Wm + (size_t)(wblk + row) * D_ + k0 + kc * 8,
                    Bs + (i * 256 + wave * 64) * 8);
        }
        __syncthreads();

        #pragma unroll
        for (int kk = 0; kk < 2; ++kk) {
            bf16x8 af[4], bfm[4];
            if (swapped) {
                #pragma unroll
                for (int mi = 0; mi < 4; ++mi)
                    af[mi] = ldg8(&Bs[(kk * 512 + (ta + mi) * 64 + lane) * 8]);
                #pragma unroll
                for (int ni = 0; ni < 4; ++ni)
                    bfm[ni] = ldg8(&As[(kk * 512 + (tb + ni) * 64 + lane) * 8]);
            } else {
                #pragma unroll
                for (int mi = 0; mi < 4; ++mi)
                    af[mi] = ldg8(&As[(kk * 512 + (ta + mi) * 64 + lane) * 8]);
                #pragma unroll
                for (int ni = 0; ni < 4; ++ni)
                    bfm[ni] = ldg8(&Bs[(kk * 512 + (tb + ni) * 64 + lane) * 8]);
            }
            #pragma unroll
            for (int mi = 0; mi < 4; ++mi)
                #pragma unroll
                for (int ni = 0; ni < 4; ++ni)
                    acc[mi][ni] = MFMA16(af[mi], bfm[ni], acc[mi][ni]);
        }
    }

    if (MODE == 1) {
        float* Y = (float*)OutBase;
        #pragma unroll
        for (int mi = 0; mi < 4; ++mi)
            #pragma unroll
            for (int ni = 0; ni < 4; ++ni) {
                const int s = xblk + (tb + ni) * 16 + lc;
                const int d = wblk + (ta + mi) * 16 + lg * 4;
                *reinterpret_cast<f32x4*>(
                    &Y[(size_t)s * D_ + d]) = acc[mi][ni];
            }
    } else if (z < 2) {
        bf16* Y = (bf16*)OutBase + (size_t)z * M_ * D_;
        const float sc = (z == 0) ? 0.125f * 1.4426950408889634f : 1.0f;
        #pragma unroll
        for (int mi = 0; mi < 4; ++mi)
            #pragma unroll
            for (int ni = 0; ni < 4; ++ni) {
                const int s = xblk + (tb + ni) * 16 + lc;
                const int d = wblk + (ta + mi) * 16 + lg * 4;
                bf16x4 v;
                #pragma unroll
                for (int r = 0; r < 4; ++r) v[r] = (bf16)(acc[mi][ni][r] * sc);
                const size_t oidx =
                    ((((size_t)(s >> 11) * H_ + (d >> 6)) * S_
                      + (s & (S_ - 1))) << 6) + (d & 63);
                *reinterpret_cast<bf16x4*>(&Y[oidx]) = v;
            }
    } else {
        bf16* Y = (bf16*)OutBase + (size_t)z * M_ * D_;
        #pragma unroll
        for (int mi = 0; mi < 4; ++mi)
            #pragma unroll
            for (int ni = 0; ni < 4; ++ni) {
                const int s0  = xblk + (ta + mi) * 16 + lg * 4;
                const int col = wblk + (tb + ni) * 16 + lc;
                bf16x4 v;
                #pragma unroll
                for (int r = 0; r < 4; ++r) v[r] = (bf16)acc[mi][ni][r];
                const size_t oidx =
                    ((((size_t)(s0 >> 11)) * H_ + (col >> 6)) << 17)
                    + (size_t)(col & 63) * S_ + (s0 & (S_ - 1));
                *reinterpret_cast<bf16x4*>(&Y[oidx]) = v;
            }
    }
}

// ---------------------------------------------------------------------------
// Causal flash attention, operand-swapped, frag-major LDS, double-buffered,
// PAIRED for uniform load: block p processes q-tiles p and 31-p sequentially
// (p+1 + 32-p = 33 k-iters, identical for every block). Grid 512.
// Q pre-scaled by 0.125*log2e (folded into its projection) -> softmax in
// log2 domain with no per-element scaling.
// ---------------------------------------------------------------------------
__global__ __launch_bounds__(256) void attn(
    const bf16* __restrict__ QKV, bf16* __restrict__ Ctx)
{
    const int bh = blockIdx.y;
    const int b = bh >> 3, h = bh & 7;
    const int p = blockIdx.x;
    const size_t plane = (size_t)S_ * DK_;
    const bf16* Q  = QKV + (size_t)bh * plane;
    const bf16* Kp = QKV + (size_t)(B_ * H_) * plane + (size_t)bh * plane;
    const bf16* Vt = QKV + 2 * (size_t)(B_ * H_) * plane + (size_t)bh * plane;

    const int lane = threadIdx.x & 63;
    const int wave = threadIdx.x >> 6;
    const int lc = lane & 15;
    const int lg = lane >> 4;
    const int srow = wave * 16 + lc;

    __shared__ bf16 Ks[2][64 * 64];
    __shared__ bf16 Vs[2][64 * 64];
    __shared__ bf16 Pw[4][128 * 8];

    #pragma unroll
    for (int ph = 0; ph < 2; ++ph) {
        const int jq = ph ? (31 - p) : p;
        const int q0 = jq * 64;
        const int ntiles = jq + 1;
        const int q = q0 + wave * 16 + lc;

        // Q B-frag (already scaled by 0.125*log2e)
        bf16x8 qf0 = ldg8(Q + (size_t)q * DK_ + lg * 8);
        bf16x8 qf1 = ldg8(Q + (size_t)q * DK_ + 32 + lg * 8);

        f32x4 accO[4] = {};
        float mi = -1e30f, li = 0.f;

        __syncthreads();              // buffers free from previous phase
        #pragma unroll
        for (int i = 0; i < 2; ++i) { // prologue: stage tile 0 -> buf 0
            const int kc = i * 4 + lg;
            async16(Kp + (size_t)srow * DK_ + kc * 8, Ks[0] + (i * 256 + wave * 64) * 8);
            async16(Vt + (size_t)srow * S_ + kc * 8,  Vs[0] + (i * 256 + wave * 64) * 8);
        }

        for (int j = 0; j < ntiles; ++j) {
            __syncthreads();          // tile j staged; buf j-1 readers done
            if (j + 1 < ntiles) {
                const int kn = (j + 1) * 64;
                bf16* kd = Ks[(j + 1) & 1];
                bf16* vd = Vs[(j + 1) & 1];
                #pragma unroll
                for (int i = 0; i < 2; ++i) {
                    const int kc = i * 4 + lg;
                    async16(Kp + (size_t)(kn + srow) * DK_ + kc * 8,
                            kd + (i * 256 + wave * 64) * 8);
                    async16(Vt + (size_t)srow * S_ + kn + kc * 8,
                            vd + (i * 256 + wave * 64) * 8);
                }
            }
            const int k0 = j * 64;
            const bf16* ks = Ks[j & 1];
            const bf16* vs = Vs[j & 1];

            // ---- S^T = K Q^T (C: col=q=lc, row=k=t*16+lg*4+r), log2 domain -
            f32x4 st[4];
            #pragma unroll
            for (int t = 0; t < 4; ++t) {
                bf16x8 kf0 = ldg8(&ks[(t * 64 + lane) * 8]);
                bf16x8 kf1 = ldg8(&ks[(256 + t * 64 + lane) * 8]);
                f32x4 zz = {};
                zz = MFMA16(kf0, qf0, zz);
                st[t] = MFMA16(kf1, qf1, zz);
            }

            // ---- mask (diagonal tile only) + running max -------------------
            float mx = mi;
            if (k0 + 64 > q0 + wave * 16) {
                #pragma unroll
                for (int t = 0; t < 4; ++t)
                    #pragma unroll
                    for (int r = 0; r < 4; ++r) {
                        const int kpos = k0 + t * 16 + lg * 4 + r;
                        const float s = (kpos <= q) ? st[t][r] : -1e30f;
                        st[t][r] = s;
                        mx = fmaxf(mx, s);
                    }
            } else {
                #pragma unroll
                for (int t = 0; t < 4; ++t)
                    #pragma unroll
                    for (int r = 0; r < 4; ++r) mx = fmaxf(mx, st[t][r]);
            }
            mx = fmaxf(mx, __shfl_xor(mx, 16));
            mx = fmaxf(mx, __shfl_xor(mx, 32));

            // ---- rescale only if a new max appeared (wave-uniform) ---------
            if (__any(mx > mi)) {
                const float alpha = EXP2(mi - mx);
                li *= alpha;
                #pragma unroll
                for (int t = 0; t < 4; ++t)
                    #pragma unroll
                    for (int r = 0; r < 4; ++r) accO[t][r] *= alpha;
            }
            mi = mx;

            float rs = 0.f;
            #pragma unroll
            for (int t = 0; t < 4; ++t)
                #pragma unroll
                for (int r = 0; r < 4; ++r) {
                    const float pv = EXP2(st[t][r] - mx);
                    st[t][r] = pv;
                    rs += pv;
                }
            rs += __shfl_xor(rs, 16);
            rs += __shfl_xor(rs, 32);
            li += rs;

            // ---- P to per-wave LDS (chunk-major [kc][q]) -------------------
            bf16* Pp = &Pw[wave][0];
            #pragma unroll
            for (int t = 0; t < 4; ++t) {
                bf16x4 pv;
                #pragma unroll
                for (int r = 0; r < 4; ++r) pv[r] = (bf16)st[t][r];
                *reinterpret_cast<bf16x4*>(
                    &Pp[((2 * t + (lg >> 1)) * 16 + lc) * 8 + (lg & 1) * 4]) = pv;
            }
            bf16x8 p0 = ldg8(&Pp[lane * 8]);
            bf16x8 p1 = ldg8(&Pp[(64 + lane) * 8]);

            // ---- O^T += V^T P ----------------------------------------------
            #pragma unroll
            for (int t = 0; t < 4; ++t) {
                bf16x8 v0 = ldg8(&vs[(t * 64 + lane) * 8]);
                bf16x8 v1 = ldg8(&vs[(256 + t * 64 + lane) * 8]);
                accO[t] = MFMA16(v0, p0, accO[t]);
                accO[t] = MFMA16(v1, p1, accO[t]);
            }
        }

        // ---- epilogue for this phase ---------------------------------------
        const float rl = 1.0f / li;
        #pragma unroll
        for (int t = 0; t < 4; ++t) {
            bf16x4 ov;
            #pragma unroll
            for (int r = 0; r < 4; ++r) ov[r] = (bf16)(accO[t][r] * rl);
            const int d = t * 16 + lg * 4;
            *reinterpret_cast<bf16x4*>(
                &Ctx[((size_t)b * S_ + q) * D_ + h * 64 + d]) = ov;
        }
        __syncthreads();              // all reads of bufs done before next phase
    }
}

extern "C" void kernel_launch(void* const* d_in, const int* in_sizes, int n_in,
                              void* d_out, int out_size, void* d_ws, size_t ws_size,
                              hipStream_t stream)
{
    float* out = (float*)d_out;

    bf16* Xb  = (bf16*)d_ws;                          // [3][M_][D_]
    bf16* Wb  = Xb + (size_t)3 * M_ * D_;             // [4][D_][D_]
    bf16* qkv = Wb + (size_t)4 * D_ * D_;             // Q,K [bh][s][64]; V^T [bh][d][s]
    bf16* ctx = qkv + (size_t)3 * M_ * D_;            // [M_][D_]

    cvt_all<<<6656, 256, 0, stream>>>(
        (const float*)d_in[0], (const float*)d_in[1], (const float*)d_in[2],
        (const float*)d_in[3], (const float*)d_in[4], (const float*)d_in[5],
        (const float*)d_in[6], Xb);

    gemm_proj<0><<<dim3(D_ / 128, M_ / 128, 3), 256, 0, stream>>>(Xb, Wb, qkv);
    attn<<<dim3(16, B_ * H_), 256, 0, stream>>>(qkv, ctx);
    gemm_proj<1><<<dim3(D_ / 128, M_ / 128), 256, 0, stream>>>(ctx, Wb, out);
}